// Round 7
// baseline (50.849 us; speedup 1.0000x reference)
//
#include <hip/hip_runtime.h>

#define HW 224
#define CHW (HW*HW)

__global__ __launch_bounds__(256) void patch_conv_kernel(
    const float* __restrict__ X,    // [B][3][224][224]
    const float* __restrict__ Wt,   // [3][3][3][3] OIHW
    const float* __restrict__ Bv,   // [3]
    const float* __restrict__ P,    // [3136][48]
    float* __restrict__ out)        // [B][196][768]
{
    const int tid  = threadIdx.x;
    const int lane = tid & 63;
    const int wv   = tid >> 6;
    const int fr   = blockIdx.x;            // fine patch row 0..55 (y>>2)
    const int y    = fr * 4 + wv;           // image row; block covers rows 4fr..4fr+3
    const int b    = blockIdx.y;
    const int x0   = lane * 4;              // 0..252
    const bool act = (x0 < HW);             // lanes 56..63: staging/shfl only

    // ---- stage this fine-row's P slice into LDS: [56 nf][48 vals], stride 50
    // (stride 50 words => 18*l mod 32 bank pattern: 2-way aliasing = free)
    __shared__ float pl[56 * 50];
    {
        const float2* Ps = (const float2*)(P + fr * (56 * 48));
        for (int i = tid; i < 56 * 24; i += 256) {       // 1344 float2
            int r = i / 24;
            int c = (i - r * 24) * 2;
            *(float2*)&pl[r * 50 + c] = Ps[i];
        }
    }

    // weights: wave-uniform -> SGPRs
    float w[81];
    #pragma unroll
    for (int i = 0; i < 81; ++i) w[i] = Wt[i];
    const float bias[3] = { Bv[0], Bv[1], Bv[2] };

    __syncthreads();

    // ---- batched X loads: 9 float4 + 18 shfl, all lanes execute (v=0 if inactive)
    const float* Xb = X + (size_t)b * (3 * CHW);
    float rr[3][3][6];                      // [ci][ky][x0-1 .. x0+4]
    #pragma unroll
    for (int ci = 0; ci < 3; ++ci) {
        #pragma unroll
        for (int ky = 0; ky < 3; ++ky) {
            const int ry = y - 1 + ky;
            float4 v = make_float4(0.f, 0.f, 0.f, 0.f);
            if ((unsigned)ry < HW && act)
                v = *(const float4*)(Xb + ci * CHW + ry * HW + x0);
            float lf = __shfl_up(v.w, 1);
            float rt = __shfl_down(v.x, 1);
            if (lane == 0) lf = 0.f;
            if (x0 + 4 >= HW) rt = 0.f;
            rr[ci][ky][0] = lf;
            rr[ci][ky][1] = v.x; rr[ci][ky][2] = v.y;
            rr[ci][ky][3] = v.z; rr[ci][ky][4] = v.w;
            rr[ci][ky][5] = rt;
        }
    }

    if (!act) return;                       // no barriers past this point

    // ---- acc init: bias + P (from LDS; nf = fr*56 + lane, sub = wv*4)
    float acc[3][4];
    #pragma unroll
    for (int co = 0; co < 3; ++co) {
        const int base = lane * 50 + co * 16 + wv * 4;  // even -> 8B aligned
        float2 pa = *(const float2*)&pl[base];
        float2 pb = *(const float2*)&pl[base + 2];
        acc[co][0] = bias[co] + pa.x; acc[co][1] = bias[co] + pa.y;
        acc[co][2] = bias[co] + pb.x; acc[co][3] = bias[co] + pb.y;
    }

    // ---- 324 FMAs
    #pragma unroll
    for (int ci = 0; ci < 3; ++ci)
        #pragma unroll
        for (int ky = 0; ky < 3; ++ky) {
            const float* r = rr[ci][ky];
            #pragma unroll
            for (int co = 0; co < 3; ++co) {
                const float* wp = w + (co * 3 + ci) * 9 + ky * 3;
                #pragma unroll
                for (int j = 0; j < 4; ++j)
                    acc[co][j] += wp[0] * r[j] + wp[1] * r[j + 1] + wp[2] * r[j + 2];
            }
        }

    // ---- store: out[b, nc, co*256 + (y&15)*16 + (x0&15)]
    const int nc = (y >> 4) * 14 + (x0 >> 4);
    float* op = out + (size_t)b * (196 * 768) + nc * 768 + (y & 15) * 16 + (x0 & 15);
    #pragma unroll
    for (int co = 0; co < 3; ++co)
        *(float4*)(op + co * 256) =
            make_float4(acc[co][0], acc[co][1], acc[co][2], acc[co][3]);
}

extern "C" void kernel_launch(void* const* d_in, const int* in_sizes, int n_in,
                              void* d_out, int out_size, void* d_ws, size_t ws_size,
                              hipStream_t stream) {
    const float* X  = (const float*)d_in[0];
    const float* Wt = (const float*)d_in[1];
    const float* Bv = (const float*)d_in[2];
    const float* P  = (const float*)d_in[3];
    float* out = (float*)d_out;

    // block = 4 waves = rows of one fine patch row; 56 fine rows x 128 images
    dim3 grid(56, 128);
    patch_conv_kernel<<<grid, 256, 0, stream>>>(X, Wt, Bv, P, out);
}